// Round 15
// baseline (212.100 us; speedup 1.0000x reference)
//
#include <hip/hip_runtime.h>
#include <hip/hip_fp16.h>

static constexpr int NN  = 10000;    // nodes
static constexpr int NE  = 640000;   // edges
static constexpr int INC = 128;
static constexpr int HIDC = 256;
static constexpr int OUTC = 128;
static constexpr int CAP = 128;      // ELL row capacity (max in-degree ~104)

static constexpr int FB = 128;       // fill/count slice blocks (5000 edges each)
static constexpr int CB = 64;        // csum slice blocks (10000 edges each)
static constexpr int HB = 313;       // half-scale blocks (1024 thr * 4 floats)
static constexpr int TB = 32;        // W1 transpose blocks
static constexpr int NP = 10240;     // padded node stride
static constexpr int NG = 625;       // fused blocks = 16-node groups
static constexpr int XROW = 136;     // LDS A-tile row stride in halves (272B, 16B-aligned)

typedef _Float16 half8 __attribute__((ext_vector_type(8)));
typedef float f32x4 __attribute__((ext_vector_type(4)));

// ---- workspace layout (bytes); ws_size ~256 MB ----
static constexpr size_t OFF_DONE  = 0;          // uint[1]
static constexpr size_t OFF_VP    = 1024;       // float[64*256] = 65,536
static constexpr size_t OFF_CNT   = 66560;      // int[10240]
static constexpr size_t OFF_DINV  = 107520;     // float[10240]
static constexpr size_t OFF_ELL   = 148480;     // ushort[10000*128] = 2,560,000 (j-permuted)
static constexpr size_t OFF_XH    = 2708480;    // half[10000*128]   = 2,560,000
static constexpr size_t OFF_CPART = 5268480;    // ushort[128*10240] = 2,621,440
static constexpr size_t OFF_CSP   = 7889920;    // float[64*10240]   = 2,621,440
static constexpr size_t OFF_W1T   = 10511360;   // half[256*128]     = 65,536

// ---- K1: slice-parallel degree count (LDS histogram). Block 0 also zeroes
// vpart/done (consumed two dispatches later; stream order guarantees vis). ----
__global__ __launch_bounds__(1024) void k_count(const int* __restrict__ ei,
                                                unsigned short* __restrict__ cpart,
                                                float* __restrict__ vpart,
                                                unsigned int* __restrict__ done) {
    __shared__ int lh[NN];
    int t = threadIdx.x, b = blockIdx.x;
    if (b == 0) {
        for (int i = t; i < 64 * HIDC; i += 1024) vpart[i] = 0.f;
        if (t == 0) *done = 0u;
    }
    for (int i = t; i < NN; i += 1024) lh[i] = 0;
    __syncthreads();
    int e0 = b * (NE / FB);
    for (int k = t; k < NE / FB; k += 1024) atomicAdd(&lh[ei[NE + e0 + k]], 1);
    __syncthreads();
    for (int i = t; i < NN; i += 1024) cpart[b * NP + i] = (unsigned short)lh[i];
}

// ---- K2: per-node scan of partials -> per-block offsets, cnt, dinv ----
__global__ __launch_bounds__(1024) void k_scan(unsigned short* __restrict__ cpart,
                                               int* __restrict__ cnt,
                                               float* __restrict__ dinv) {
    int n = blockIdx.x * 1024 + threadIdx.x;
    if (n >= NN) return;
    int run = 0;
#pragma unroll 8
    for (int b = 0; b < FB; b++) {
        int c = cpart[b * NP + n];
        cpart[b * NP + n] = (unsigned short)run;
        run += c;
    }
    cnt[n] = run;
    dinv[n] = rsqrtf((float)(1 + run));   // +1 self loop
}

// ---- K3 (fused): ELL fill (j-permuted) | csum partials | fp16 X | W1^T ----
__global__ __launch_bounds__(1024) void k_prep(const int* __restrict__ ei,
                                               const float* __restrict__ x,
                                               const float* __restrict__ W1,
                                               const float* __restrict__ dinv,
                                               const unsigned short* __restrict__ cpart,
                                               unsigned short* __restrict__ ell,
                                               float* __restrict__ cspart,
                                               __half* __restrict__ xh,
                                               __half* __restrict__ w1t) {
    __shared__ int lh[NN];
    __shared__ unsigned short soff[NN];
    int t = threadIdx.x, b = blockIdx.x;
    if (b < FB) {
        for (int i = t; i < NN; i += 1024) { lh[i] = 0; soff[i] = cpart[b * NP + i]; }
        __syncthreads();
        int e0 = b * (NE / FB);
        for (int k = t; k < NE / FB; k += 1024) {
            int s = ei[e0 + k];
            int d = ei[NE + e0 + k];
            int pos = (int)soff[d] + atomicAdd(&lh[d], 1);
            if (pos < CAP)
                ell[d * CAP + (pos & 3) * 32 + (pos >> 2)] = (unsigned short)s;
        }
    } else if (b < FB + CB) {
        int bb = b - FB;
        float* lc = (float*)lh;
        for (int i = t; i < NN; i += 1024) lc[i] = 0.f;
        __syncthreads();
        int e0 = bb * (NE / CB);
        for (int k = t; k < NE / CB; k += 1024) {
            int s = ei[e0 + k];
            int d = ei[NE + e0 + k];
            atomicAdd(&lc[s], dinv[d]);
        }
        __syncthreads();
        for (int i = t; i < NN; i += 1024) cspart[bb * NP + i] = lc[i];
    } else if (b < FB + CB + HB) {
        // xh[n,:] = fp16( dinv[n] * X[n,:] )
        int gid = (b - FB - CB) * 1024 + t;
        int i = gid * 4;
        if (i < NN * INC) {
            float4 v = *(const float4*)(x + i);
            float dv = dinv[i >> 7];
            __half2 o[2] = {__floats2half2_rn(dv * v.x, dv * v.y),
                            __floats2half2_rn(dv * v.z, dv * v.w)};
            *(float2*)(xh + i) = *(float2*)o;
        }
    } else {
        int gid = (b - FB - CB - HB) * 1024 + t;
        int k = gid & 127, tc = gid >> 7;
        w1t[tc * INC + k] = __float2half(W1[k * HIDC + tc]);
    }
}

// ---- K4: fused agg + MFMA gemm, 512 threads (8 waves) per 16-node group ----
// Agg: wave w aggregates nodes base+2w, base+2w+1 sequentially (R14's exact
// proven inner loop), rows -> LDS tile. One barrier. Gemm: wave w MFMAs cols
// [32w,32w+32) against the 16 LDS rows, folds c[n]*relu(+b1), strips partials
// into vpart[64][256]; last-arriving block emits the scalar.
__global__ __launch_bounds__(512) void k_fused(const __half* __restrict__ xh,
                                               const float* __restrict__ dinv,
                                               const int* __restrict__ cnt,
                                               const unsigned short* __restrict__ ell,
                                               const float* __restrict__ cspart,
                                               const __half* __restrict__ w1t,
                                               const float* __restrict__ b1,
                                               float* __restrict__ vpart,
                                               unsigned int* __restrict__ done,
                                               const float* __restrict__ W2,
                                               const float* __restrict__ b2,
                                               const float* __restrict__ fcw,
                                               const float* __restrict__ fcb,
                                               float* __restrict__ out) {
    __shared__ _Float16 xals[16 * XROW];
    __shared__ float scsum[16];
    __shared__ float vcol[HIDC];
    __shared__ float red[256];
    __shared__ bool last;
    int b = blockIdx.x;
    int t = threadIdx.x;
    int w = t >> 6;
    int lane = t & 63;
    int base = b * 16;

    if (t < 16) scsum[t] = 0.f;
    __syncthreads();
    // inline csum for the block's 16 nodes: 16 nodes x 64 slices, 2 loads/thread
    {
        int nl = t & 15, sl = t >> 4;   // sl in [0,32)
        float s = cspart[sl * NP + base + nl] + cspart[(sl + 32) * NP + base + nl];
        atomicAdd(&scsum[nl], s);
    }

    // ---- agg phase: wave w -> nodes base+2w+rep ----
    int g = lane & 15;        // 16B chunk of the 256B fp16 row
    int j = lane >> 4;        // neighbor group
    for (int rep = 0; rep < 2; rep++) {
        int nl = w * 2 + rep;
        int n = base + nl;
        float dn = dinv[n];
        float acc[8];
#pragma unroll
        for (int k = 0; k < 8; k++) acc[k] = 0.f;
        if (j == 0) {         // self loop: xh row n IS fp16(dn*x[n]) (R13-validated)
            float4 sv = *(const float4*)(xh + n * INC + 8 * g);
            const __half2* sh = (const __half2*)&sv;
#pragma unroll
            for (int q = 0; q < 4; q++) {
                float2 f = __half22float2(sh[q]);
                acc[2 * q] = f.x; acc[2 * q + 1] = f.y;
            }
        }
        int c = cnt[n];
        int eb = n * CAP;
        for (int i = 0; i < c; i += 32) {
            uint4 ev = *(const uint4*)(ell + eb + j * 32 + (i >> 2));
            unsigned raw[8] = {ev.x & 0xffffu, ev.x >> 16, ev.y & 0xffffu, ev.y >> 16,
                               ev.z & 0xffffu, ev.z >> 16, ev.w & 0xffffu, ev.w >> 16};
            int   su[8];
            float ws[8];
            float4 xv[8];
#pragma unroll
            for (int u = 0; u < 8; u++) {
                int idx = i + 4 * u + j;
                bool act = idx < c;
                su[u] = act ? (int)raw[u] : n;
                ws[u] = act ? 1.f : 0.f;
            }
#pragma unroll
            for (int u = 0; u < 8; u++)
                xv[u] = *(const float4*)(xh + su[u] * INC + 8 * g);
#pragma unroll
            for (int u = 0; u < 8; u++) {
                const __half2* h2 = (const __half2*)&xv[u];
#pragma unroll
                for (int q = 0; q < 4; q++) {
                    float2 f = __half22float2(h2[q]);
                    acc[2 * q]     = fmaf(ws[u], f.x, acc[2 * q]);
                    acc[2 * q + 1] = fmaf(ws[u], f.y, acc[2 * q + 1]);
                }
            }
        }
#pragma unroll
        for (int k = 0; k < 8; k++) {
            acc[k] += __shfl_down(acc[k], 32);
            acc[k] += __shfl_down(acc[k], 16);
        }
        if (j == 0) {
            __half2 o[4];
#pragma unroll
            for (int q = 0; q < 4; q++)
                o[q] = __floats2half2_rn(dn * acc[2 * q], dn * acc[2 * q + 1]);
            *(half8*)(xals + nl * XROW + g * 8) = *(half8*)o;
        }
    }
    __syncthreads();

    // ---- gemm phase: wave w -> cols [32w, 32w+32), rows = 16 LDS nodes ----
    int m = lane & 15;
    int quad = lane >> 4;
    const half8* w8 = (const half8*)w1t;
#pragma unroll
    for (int tt = 0; tt < 2; tt++) {
        int col = w * 32 + tt * 16 + m;
        f32x4 acc4 = {0.f, 0.f, 0.f, 0.f};
#pragma unroll
        for (int k0 = 0; k0 < 4; k0++) {
            half8 af = *(const half8*)(xals + m * XROW + (k0 * 4 + quad) * 8);
            half8 bf = w8[col * 16 + k0 * 4 + quad];
            acc4 = __builtin_amdgcn_mfma_f32_16x16x32_f16(af, bf, acc4, 0, 0, 0);
        }
        float bcol = b1[col];
        float p = 0.f;
#pragma unroll
        for (int r = 0; r < 4; r++) {
            int nl = quad * 4 + r;
            float dnn = dinv[base + nl];
            float cn = dnn * (dnn + scsum[nl]);
            p += cn * fmaxf(acc4[r] + bcol, 0.f);
        }
        p += __shfl_down(p, 16);
        p += __shfl_down(p, 32);
        if (lane < 16) vcol[w * 32 + tt * 16 + lane] = p;  // wave-disjoint cols
    }
    __syncthreads();
    if (t < HIDC) atomicAdd(&vpart[(b & 63) * HIDC + t], vcol[t]);
    __threadfence();
    if (t == 0) {
        unsigned int old = __hip_atomic_fetch_add(done, 1u, __ATOMIC_ACQ_REL,
                                                  __HIP_MEMORY_SCOPE_AGENT);
        last = (old == (unsigned)NG - 1);
    }
    __syncthreads();
    if (!last) return;
    // ---- final scalar: out = (1/N)*sum_t v[t]*u[t] + b2.fc_w + fc_b ----
    if (t < 256) {
        float vt = 0.f;
#pragma unroll 8
        for (int row = 0; row < 64; row++)
            vt += __hip_atomic_load(&vpart[row * HIDC + t], __ATOMIC_RELAXED,
                                    __HIP_MEMORY_SCOPE_AGENT);
        float u = 0.f;
#pragma unroll 4
        for (int jj = 0; jj < OUTC; jj++) u = fmaf(W2[t * OUTC + jj], fcw[jj], u);
        float contrib = vt * u * (1.0f / (float)NN);
        if (t < OUTC) contrib += b2[t] * fcw[t];
        red[t] = contrib;
    }
    __syncthreads();
    for (int s = 128; s > 0; s >>= 1) {
        if (t < s) red[t] += red[t + s];
        __syncthreads();
    }
    if (t == 0) out[0] = red[0] + fcb[0];
}

extern "C" void kernel_launch(void* const* d_in, const int* in_sizes, int n_in,
                              void* d_out, int out_size, void* d_ws, size_t ws_size,
                              hipStream_t stream) {
    const float* x   = (const float*)d_in[0];
    const int*   ei  = (const int*)d_in[1];
    const float* W1  = (const float*)d_in[2];
    const float* b1  = (const float*)d_in[3];
    const float* W2  = (const float*)d_in[4];
    const float* b2  = (const float*)d_in[5];
    const float* fcw = (const float*)d_in[6];
    const float* fcb = (const float*)d_in[7];
    float* out = (float*)d_out;

    char* ws = (char*)d_ws;
    unsigned int*   done   = (unsigned int*)(ws + OFF_DONE);
    float*          vpart  = (float*)(ws + OFF_VP);
    int*            cnt    = (int*)(ws + OFF_CNT);
    float*          dinv   = (float*)(ws + OFF_DINV);
    unsigned short* ell    = (unsigned short*)(ws + OFF_ELL);
    __half*         xh     = (__half*)(ws + OFF_XH);
    unsigned short* cpart  = (unsigned short*)(ws + OFF_CPART);
    float*          cspart = (float*)(ws + OFF_CSP);
    __half*         w1t    = (__half*)(ws + OFF_W1T);

    k_count<<<FB, 1024, 0, stream>>>(ei, cpart, vpart, done);
    k_scan<<<10, 1024, 0, stream>>>(cpart, cnt, dinv);
    k_prep<<<FB + CB + HB + TB, 1024, 0, stream>>>(ei, x, W1, dinv, cpart, ell,
                                                   cspart, xh, w1t);
    k_fused<<<NG, 512, 0, stream>>>(xh, dinv, cnt, ell, cspart, w1t, b1,
                                    vpart, done, W2, b2, fcw, fcb, out);
}

// Round 16
// 157.244 us; speedup vs baseline: 1.3489x; 1.3489x over previous
//
#include <hip/hip_runtime.h>
#include <hip/hip_fp16.h>

static constexpr int NN  = 10000;    // nodes
static constexpr int NE  = 640000;   // edges
static constexpr int INC = 128;
static constexpr int HIDC = 256;
static constexpr int OUTC = 128;
static constexpr int CAP = 128;      // ELL row capacity (max in-degree ~104)

static constexpr int FB = 256;       // fill/count slice blocks (2500 edges each; 1/CU)
static constexpr int CB = 64;        // csum slice blocks (10000 edges each)
static constexpr int HB = 313;       // half-scale blocks (1024 thr * 4 floats)
static constexpr int TB = 32;        // W1 transpose blocks (ride along k_count)
static constexpr int AB = 2500;      // agg blocks (4 nodes each)
static constexpr int NP = 10240;     // padded node stride
static constexpr int GG = 256;       // gemm blocks
static constexpr int NG = 625;       // 16-node groups

typedef _Float16 half8 __attribute__((ext_vector_type(8)));
typedef float f32x4 __attribute__((ext_vector_type(4)));

// ---- workspace layout (bytes); ws_size ~256 MB ----
static constexpr size_t OFF_DONE  = 0;          // uint[1]
static constexpr size_t OFF_V     = 64;         // float[256]
static constexpr size_t OFF_CNT   = 2048;       // int[10240]
static constexpr size_t OFF_DINV  = 43008;      // float[10240]
static constexpr size_t OFF_CSUM  = 83968;      // float[10240]
static constexpr size_t OFF_ELL   = 124928;     // ushort[10000*128] = 2,560,000 (j-permuted)
static constexpr size_t OFF_XH    = 2684928;    // half[10000*128]   = 2,560,000
static constexpr size_t OFF_XA    = 5244928;    // half[10000*128]   = 2,560,000
static constexpr size_t OFF_CPART = 7804928;    // ushort[256*10240] = 5,242,880
static constexpr size_t OFF_CSP   = 13047808;   // float[64*10240]   = 2,621,440
static constexpr size_t OFF_W1T   = 15669248;   // half[256*128]     = 65,536

// ---- K1: slice-parallel degree count (LDS histogram), 1 block/CU.
// Block 0 zeroes v/done; tail blocks transpose W1 (no dependencies). ----
__global__ __launch_bounds__(1024) void k_count(const int* __restrict__ ei,
                                                const float* __restrict__ W1,
                                                unsigned short* __restrict__ cpart,
                                                __half* __restrict__ w1t,
                                                float* __restrict__ v,
                                                unsigned int* __restrict__ done) {
    int t = threadIdx.x, b = blockIdx.x;
    if (b >= FB) {            // W1^T: w1t[tc][k] = fp16(W1[k][tc])
        int gid = (b - FB) * 1024 + t;
        int k = gid & 127, tc = gid >> 7;
        w1t[tc * INC + k] = __float2half(W1[k * HIDC + tc]);
        return;
    }
    __shared__ int lh[NN];
    if (b == 0) {
        if (t < 256) v[t] = 0.f;
        if (t == 256) *done = 0u;
    }
    for (int i = t; i < NN; i += 1024) lh[i] = 0;
    __syncthreads();
    int e0 = b * (NE / FB);
    for (int k = t; k < NE / FB; k += 1024) atomicAdd(&lh[ei[NE + e0 + k]], 1);
    __syncthreads();
    for (int i = t; i < NN; i += 1024) cpart[b * NP + i] = (unsigned short)lh[i];
}

// ---- K2: per-node scan of partials -> per-block offsets, cnt, dinv ----
__global__ __launch_bounds__(256) void k_scan(unsigned short* __restrict__ cpart,
                                              int* __restrict__ cnt,
                                              float* __restrict__ dinv) {
    int n = blockIdx.x * 256 + threadIdx.x;
    if (n >= NN) return;
    int run = 0;
#pragma unroll 8
    for (int b = 0; b < FB; b++) {
        int c = cpart[b * NP + n];
        cpart[b * NP + n] = (unsigned short)run;
        run += c;
    }
    cnt[n] = run;
    dinv[n] = rsqrtf((float)(1 + run));   // +1 self loop
}

// ---- K3 (fused): ELL fill (j-permuted) | csum partials | fp16 X scale ----
// ELL slot(pos) = (pos&3)*32 + (pos>>2): group-j entries for unroll-block i
// are contiguous at [j*32 + (i>>2), +8) -> one 16B load in k_agg.
__global__ __launch_bounds__(1024) void k_prep(const int* __restrict__ ei,
                                               const float* __restrict__ x,
                                               const float* __restrict__ dinv,
                                               const unsigned short* __restrict__ cpart,
                                               unsigned short* __restrict__ ell,
                                               float* __restrict__ cspart,
                                               __half* __restrict__ xh) {
    __shared__ int lh[NN];
    __shared__ unsigned short soff[NN];
    int t = threadIdx.x, b = blockIdx.x;
    if (b < FB) {
        for (int i = t; i < NN; i += 1024) { lh[i] = 0; soff[i] = cpart[b * NP + i]; }
        __syncthreads();
        int e0 = b * (NE / FB);
        for (int k = t; k < NE / FB; k += 1024) {
            int s = ei[e0 + k];
            int d = ei[NE + e0 + k];
            int pos = (int)soff[d] + atomicAdd(&lh[d], 1);
            if (pos < CAP)
                ell[d * CAP + (pos & 3) * 32 + (pos >> 2)] = (unsigned short)s;
        }
    } else if (b < FB + CB) {
        int bb = b - FB;
        float* lc = (float*)lh;
        for (int i = t; i < NN; i += 1024) lc[i] = 0.f;
        __syncthreads();
        int e0 = bb * (NE / CB);
        for (int k = t; k < NE / CB; k += 1024) {
            int s = ei[e0 + k];
            int d = ei[NE + e0 + k];
            atomicAdd(&lc[s], dinv[d]);
        }
        __syncthreads();
        for (int i = t; i < NN; i += 1024) cspart[bb * NP + i] = lc[i];
    } else {
        // xh[n,:] = fp16( dinv[n] * X[n,:] )
        int gid = (b - FB - CB) * 1024 + t;
        int i = gid * 4;
        if (i < NN * INC) {
            float4 v = *(const float4*)(x + i);
            float dv = dinv[i >> 7];
            __half2 o[2] = {__floats2half2_rn(dv * v.x, dv * v.y),
                            __floats2half2_rn(dv * v.z, dv * v.w)};
            *(float2*)(xh + i) = *(float2*)o;
        }
    }
}

// ---- K4 (fused): aggregation gather | csum reduce ----
// Xa[n] = fp16( dinv[n]*(dinv[n]*X[n] + sum_s xh[s]) ); xh pre-scaled by dinv[s].
// Wave=node; lane = g + 16*j; 8 rows in flight. ELL read = ONE 16B load per
// lane per iter (j-permuted layout). fp32 fmaf accumulate (R8/R14-proven form).
__global__ __launch_bounds__(256) void k_agg(const float* __restrict__ x,
                                             const __half* __restrict__ xh,
                                             const float* __restrict__ dinv,
                                             const int* __restrict__ cnt,
                                             const unsigned short* __restrict__ ell,
                                             const float* __restrict__ cspart,
                                             float* __restrict__ csum,
                                             __half* __restrict__ xa) {
    int b = blockIdx.x;
    if (b >= AB) {   // csum partial reduce (40 tail blocks)
        int n = (b - AB) * 256 + threadIdx.x;
        if (n < NN) {
            float s = 0.f;
#pragma unroll
            for (int bb = 0; bb < CB; bb++) s += cspart[bb * NP + n];
            csum[n] = s;
        }
        return;
    }
    int lane = threadIdx.x & 63;
    int n = b * 4 + (threadIdx.x >> 6);
    int g = lane & 15;        // 16B chunk of the 256B fp16 row
    int j = lane >> 4;        // neighbor group
    float dn = dinv[n];
    float acc[8];
#pragma unroll
    for (int k = 0; k < 8; k++) acc[k] = 0.f;
    if (j == 0) {             // self loop from fp32 X (outer dn applied at end)
        const float4* x4 = (const float4*)x;
        float4 a = x4[n * 32 + 2 * g];
        float4 c4 = x4[n * 32 + 2 * g + 1];
        acc[0] = dn * a.x;  acc[1] = dn * a.y;  acc[2] = dn * a.z;  acc[3] = dn * a.w;
        acc[4] = dn * c4.x; acc[5] = dn * c4.y; acc[6] = dn * c4.z; acc[7] = dn * c4.w;
    }
    int c = cnt[n];
    int base = n * CAP;
    for (int i = 0; i < c; i += 32) {
        // one 16B load: this j-group's 8 ELL entries for idx = i + 4u + j
        uint4 ev = *(const uint4*)(ell + base + j * 32 + (i >> 2));
        unsigned raw[8] = {ev.x & 0xffffu, ev.x >> 16, ev.y & 0xffffu, ev.y >> 16,
                           ev.z & 0xffffu, ev.z >> 16, ev.w & 0xffffu, ev.w >> 16};
        int   su[8];
        float ws[8];
        float4 xv[8];
#pragma unroll
        for (int u = 0; u < 8; u++) {
            int idx = i + 4 * u + j;
            bool act = idx < c;
            su[u] = act ? (int)raw[u] : n;   // in-bounds safe row when inactive
            ws[u] = act ? 1.f : 0.f;
        }
#pragma unroll
        for (int u = 0; u < 8; u++)
            xv[u] = *(const float4*)(xh + su[u] * INC + 8 * g);
#pragma unroll
        for (int u = 0; u < 8; u++) {
            const __half2* h2 = (const __half2*)&xv[u];
#pragma unroll
            for (int q = 0; q < 4; q++) {
                float2 f = __half22float2(h2[q]);
                acc[2 * q]     = fmaf(ws[u], f.x, acc[2 * q]);
                acc[2 * q + 1] = fmaf(ws[u], f.y, acc[2 * q + 1]);
            }
        }
    }
#pragma unroll
    for (int k = 0; k < 8; k++) {
        acc[k] += __shfl_down(acc[k], 32);
        acc[k] += __shfl_down(acc[k], 16);
    }
    if (j == 0) {
        __half2 o[4];
#pragma unroll
        for (int q = 0; q < 4; q++)
            o[q] = __floats2half2_rn(dn * acc[2 * q], dn * acc[2 * q + 1]);
        *(float4*)(xa + n * INC + 8 * g) = *(float4*)o;
    }
}

// ---- K5: MFMA GEMM + weighted-relu reduction + fused final scalar ----
__global__ __launch_bounds__(256) void k_gemm(const __half* __restrict__ xa,
                                              const __half* __restrict__ w1t,
                                              const float* __restrict__ b1,
                                              const float* __restrict__ dinv,
                                              const float* __restrict__ csum,
                                              float* __restrict__ v,
                                              unsigned int* __restrict__ done,
                                              const float* __restrict__ W2,
                                              const float* __restrict__ b2,
                                              const float* __restrict__ fcw,
                                              const float* __restrict__ fcb,
                                              float* __restrict__ out) {
    __shared__ float vloc[HIDC];
    int t = threadIdx.x;
    int w = t >> 6;           // wave id: owns cols [64w, 64w+64)
    int lane = t & 63;
    int m = lane & 15;
    int quad = lane >> 4;
    for (int i = t; i < HIDC; i += 256) vloc[i] = 0.f;
    __syncthreads();

    float bcol[4];
#pragma unroll
    for (int tt = 0; tt < 4; tt++) bcol[tt] = b1[w * 64 + tt * 16 + m];

    const half8* xa8 = (const half8*)xa;     // 8-half (16B) granules
    const half8* w8  = (const half8*)w1t;

    for (int gidx = blockIdx.x; gidx < NG; gidx += gridDim.x) {
        int base = gidx * 16;
        f32x4 acc[4] = {{0,0,0,0},{0,0,0,0},{0,0,0,0},{0,0,0,0}};
#pragma unroll
        for (int k0 = 0; k0 < 4; k0++) {
            half8 af = xa8[(base + m) * 16 + k0 * 4 + quad];
#pragma unroll
            for (int tt = 0; tt < 4; tt++) {
                int col = w * 64 + tt * 16 + m;
                half8 bf = w8[col * 16 + k0 * 4 + quad];
                acc[tt] = __builtin_amdgcn_mfma_f32_16x16x32_f16(af, bf, acc[tt], 0, 0, 0);
            }
        }
        float cr[4];
#pragma unroll
        for (int r = 0; r < 4; r++) {
            int n = base + quad * 4 + r;
            float dnn = dinv[n];
            cr[r] = dnn * (dnn + csum[n]);
        }
#pragma unroll
        for (int tt = 0; tt < 4; tt++) {
            float p = 0.f;
#pragma unroll
            for (int r = 0; r < 4; r++)
                p += cr[r] * fmaxf(acc[tt][r] + bcol[tt], 0.f);
            p += __shfl_down(p, 16);
            p += __shfl_down(p, 32);
            if (lane < 16) vloc[w * 64 + tt * 16 + lane] += p;  // wave-disjoint cols
        }
    }
    __syncthreads();
    atomicAdd(&v[t], vloc[t]);      // device-scope, distributed across blocks
    __threadfence();
    __shared__ bool last;
    if (t == 0) {
        unsigned int old = __hip_atomic_fetch_add(done, 1u, __ATOMIC_ACQ_REL,
                                                  __HIP_MEMORY_SCOPE_AGENT);
        last = (old == gridDim.x - 1);
    }
    __syncthreads();
    if (!last) return;
    // out = (1/N)*sum_t v[t]*u[t] + b2.fc_w + fc_b,  u = W2.fc_w
    float vt = __hip_atomic_load(&v[t], __ATOMIC_ACQUIRE, __HIP_MEMORY_SCOPE_AGENT);
    __shared__ float red[256];
    float u = 0.f;
#pragma unroll 4
    for (int jj = 0; jj < OUTC; jj++) u = fmaf(W2[t * OUTC + jj], fcw[jj], u);
    float contrib = vt * u * (1.0f / (float)NN);
    if (t < OUTC) contrib += b2[t] * fcw[t];
    red[t] = contrib;
    __syncthreads();
    for (int s = 128; s > 0; s >>= 1) {
        if (t < s) red[t] += red[t + s];
        __syncthreads();
    }
    if (t == 0) out[0] = red[0] + fcb[0];
}

extern "C" void kernel_launch(void* const* d_in, const int* in_sizes, int n_in,
                              void* d_out, int out_size, void* d_ws, size_t ws_size,
                              hipStream_t stream) {
    const float* x   = (const float*)d_in[0];
    const int*   ei  = (const int*)d_in[1];
    const float* W1  = (const float*)d_in[2];
    const float* b1  = (const float*)d_in[3];
    const float* W2  = (const float*)d_in[4];
    const float* b2  = (const float*)d_in[5];
    const float* fcw = (const float*)d_in[6];
    const float* fcb = (const float*)d_in[7];
    float* out = (float*)d_out;

    char* ws = (char*)d_ws;
    unsigned int*   done   = (unsigned int*)(ws + OFF_DONE);
    float*          v      = (float*)(ws + OFF_V);
    int*            cnt    = (int*)(ws + OFF_CNT);
    float*          dinv   = (float*)(ws + OFF_DINV);
    float*          csum   = (float*)(ws + OFF_CSUM);
    unsigned short* ell    = (unsigned short*)(ws + OFF_ELL);
    __half*         xh     = (__half*)(ws + OFF_XH);
    __half*         xa     = (__half*)(ws + OFF_XA);
    unsigned short* cpart  = (unsigned short*)(ws + OFF_CPART);
    float*          cspart = (float*)(ws + OFF_CSP);
    __half*         w1t    = (__half*)(ws + OFF_W1T);

    k_count<<<FB + TB, 1024, 0, stream>>>(ei, W1, cpart, w1t, v, done);
    k_scan<<<40, 256, 0, stream>>>(cpart, cnt, dinv);
    k_prep<<<FB + CB + HB, 1024, 0, stream>>>(ei, x, dinv, cpart, ell, cspart, xh);
    k_agg<<<AB + 40, 256, 0, stream>>>(x, xh, dinv, cnt, ell, cspart, csum, xa);
    k_gemm<<<GG, 256, 0, stream>>>(xa, w1t, b1, dinv, csum, v, done,
                                   W2, b2, fcw, fcb, out);
}

// Round 17
// 150.222 us; speedup vs baseline: 1.4119x; 1.0467x over previous
//
#include <hip/hip_runtime.h>
#include <hip/hip_fp16.h>

static constexpr int NN  = 10000;    // nodes
static constexpr int NE  = 640000;   // edges
static constexpr int INC = 128;
static constexpr int HIDC = 256;
static constexpr int OUTC = 128;
static constexpr int CAP = 128;      // ELL row capacity (max in-degree ~104)

static constexpr int FB = 128;       // fill/count slice blocks (5000 edges each)
static constexpr int CB = 64;        // csum slice blocks (10000 edges each)
static constexpr int HB = 313;       // half-scale blocks (1024 thr * 4 floats)
static constexpr int TB = 32;        // W1 transpose blocks
static constexpr int AB = 2500;      // agg blocks (4 nodes each)
static constexpr int NP = 10240;     // padded node stride
static constexpr int GG = 256;       // gemm blocks
static constexpr int NG = 625;       // 16-node groups

typedef _Float16 half8 __attribute__((ext_vector_type(8)));
typedef float f32x4 __attribute__((ext_vector_type(4)));

// ---- workspace layout (bytes); ws_size ~256 MB ----
static constexpr size_t OFF_DONE  = 0;          // uint[1]
static constexpr size_t OFF_V     = 64;         // float[256]
static constexpr size_t OFF_CNT   = 2048;       // int[10240]
static constexpr size_t OFF_DINV  = 43008;      // float[10240]
static constexpr size_t OFF_CSUM  = 83968;      // float[10240]
static constexpr size_t OFF_ELL   = 124928;     // ushort[10000*128] = 2,560,000 (j-permuted)
static constexpr size_t OFF_XH    = 2684928;    // half[10000*128]   = 2,560,000
static constexpr size_t OFF_XA    = 5244928;    // half[10000*128]   = 2,560,000
static constexpr size_t OFF_CPART = 7804928;    // ushort[128*10240] = 2,621,440
static constexpr size_t OFF_CSP   = 10426368;   // float[64*10240]   = 2,621,440
static constexpr size_t OFF_W1T   = 13047808;   // half[256*128]     = 65,536

// ---- K1: slice-parallel degree count (LDS histogram, no global atomics).
// Block 0 also zeroes v/done (replaces the memset dispatch; consumed only by
// k_gemm, two dispatches later in stream order). ----
__global__ __launch_bounds__(1024) void k_count(const int* __restrict__ ei,
                                                unsigned short* __restrict__ cpart,
                                                float* __restrict__ v,
                                                unsigned int* __restrict__ done) {
    __shared__ int lh[NN];
    int t = threadIdx.x, b = blockIdx.x;
    if (b == 0) {
        if (t < 256) v[t] = 0.f;
        if (t == 256) *done = 0u;
    }
    for (int i = t; i < NN; i += 1024) lh[i] = 0;
    __syncthreads();
    int e0 = b * (NE / FB);
    for (int k = t; k < NE / FB; k += 1024) atomicAdd(&lh[ei[NE + e0 + k]], 1);
    __syncthreads();
    for (int i = t; i < NN; i += 1024) cpart[b * NP + i] = (unsigned short)lh[i];
}

// ---- K2: per-node scan of partials -> per-block offsets, cnt, dinv ----
__global__ __launch_bounds__(1024) void k_scan(unsigned short* __restrict__ cpart,
                                               int* __restrict__ cnt,
                                               float* __restrict__ dinv) {
    int n = blockIdx.x * 1024 + threadIdx.x;
    if (n >= NN) return;
    int run = 0;
#pragma unroll 8
    for (int b = 0; b < FB; b++) {
        int c = cpart[b * NP + n];
        cpart[b * NP + n] = (unsigned short)run;
        run += c;
    }
    cnt[n] = run;
    dinv[n] = rsqrtf((float)(1 + run));   // +1 self loop
}

// ---- K3 (fused): ELL fill (j-permuted) | csum partials | fp16 X | W1^T ----
// ELL slot(pos) = (pos&3)*32 + (pos>>2): group-j entries for unroll-block i
// are contiguous at [j*32 + (i>>2), +8) -> one 16B load in k_agg.
__global__ __launch_bounds__(1024) void k_prep(const int* __restrict__ ei,
                                               const float* __restrict__ x,
                                               const float* __restrict__ W1,
                                               const float* __restrict__ dinv,
                                               const unsigned short* __restrict__ cpart,
                                               unsigned short* __restrict__ ell,
                                               float* __restrict__ cspart,
                                               __half* __restrict__ xh,
                                               __half* __restrict__ w1t) {
    __shared__ int lh[NN];
    __shared__ unsigned short soff[NN];
    int t = threadIdx.x, b = blockIdx.x;
    if (b < FB) {
        for (int i = t; i < NN; i += 1024) { lh[i] = 0; soff[i] = cpart[b * NP + i]; }
        __syncthreads();
        int e0 = b * (NE / FB);
        for (int k = t; k < NE / FB; k += 1024) {
            int s = ei[e0 + k];
            int d = ei[NE + e0 + k];
            int pos = (int)soff[d] + atomicAdd(&lh[d], 1);
            if (pos < CAP)
                ell[d * CAP + (pos & 3) * 32 + (pos >> 2)] = (unsigned short)s;
        }
    } else if (b < FB + CB) {
        int bb = b - FB;
        float* lc = (float*)lh;
        for (int i = t; i < NN; i += 1024) lc[i] = 0.f;
        __syncthreads();
        int e0 = bb * (NE / CB);
        for (int k = t; k < NE / CB; k += 1024) {
            int s = ei[e0 + k];
            int d = ei[NE + e0 + k];
            atomicAdd(&lc[s], dinv[d]);
        }
        __syncthreads();
        for (int i = t; i < NN; i += 1024) cspart[bb * NP + i] = lc[i];
    } else if (b < FB + CB + HB) {
        // xh[n,:] = fp16( dinv[n] * X[n,:] )
        int gid = (b - FB - CB) * 1024 + t;
        int i = gid * 4;
        if (i < NN * INC) {
            float4 v = *(const float4*)(x + i);
            float dv = dinv[i >> 7];
            __half2 o[2] = {__floats2half2_rn(dv * v.x, dv * v.y),
                            __floats2half2_rn(dv * v.z, dv * v.w)};
            *(float2*)(xh + i) = *(float2*)o;
        }
    } else {
        int gid = (b - FB - CB - HB) * 1024 + t;
        int k = gid & 127, tc = gid >> 7;
        w1t[tc * INC + k] = __float2half(W1[k * HIDC + tc]);
    }
}

// ---- K4 (fused): aggregation gather | csum reduce ----
// Xa[n] = fp16( dinv[n]*(dinv[n]*X[n] + sum_s xh[s]) ); xh pre-scaled by dinv[s].
// Wave=node; lane = g + 16*j; 8 rows in flight. ELL read = ONE 16B load per
// lane per iter (j-permuted layout). fp32 fmaf accumulate (R8-proven form).
__global__ __launch_bounds__(256) void k_agg(const float* __restrict__ x,
                                             const __half* __restrict__ xh,
                                             const float* __restrict__ dinv,
                                             const int* __restrict__ cnt,
                                             const unsigned short* __restrict__ ell,
                                             const float* __restrict__ cspart,
                                             float* __restrict__ csum,
                                             __half* __restrict__ xa) {
    int b = blockIdx.x;
    if (b >= AB) {   // csum partial reduce (40 tail blocks)
        int n = (b - AB) * 256 + threadIdx.x;
        if (n < NN) {
            float s = 0.f;
#pragma unroll
            for (int bb = 0; bb < CB; bb++) s += cspart[bb * NP + n];
            csum[n] = s;
        }
        return;
    }
    int lane = threadIdx.x & 63;
    int n = b * 4 + (threadIdx.x >> 6);
    int g = lane & 15;        // 16B chunk of the 256B fp16 row
    int j = lane >> 4;        // neighbor group
    float dn = dinv[n];
    float acc[8];
#pragma unroll
    for (int k = 0; k < 8; k++) acc[k] = 0.f;
    if (j == 0) {             // self loop from fp32 X (outer dn applied at end)
        const float4* x4 = (const float4*)x;
        float4 a = x4[n * 32 + 2 * g];
        float4 c4 = x4[n * 32 + 2 * g + 1];
        acc[0] = dn * a.x;  acc[1] = dn * a.y;  acc[2] = dn * a.z;  acc[3] = dn * a.w;
        acc[4] = dn * c4.x; acc[5] = dn * c4.y; acc[6] = dn * c4.z; acc[7] = dn * c4.w;
    }
    int c = cnt[n];
    int base = n * CAP;
    for (int i = 0; i < c; i += 32) {
        // one 16B load: this j-group's 8 ELL entries for idx = i + 4u + j
        uint4 ev = *(const uint4*)(ell + base + j * 32 + (i >> 2));
        unsigned raw[8] = {ev.x & 0xffffu, ev.x >> 16, ev.y & 0xffffu, ev.y >> 16,
                           ev.z & 0xffffu, ev.z >> 16, ev.w & 0xffffu, ev.w >> 16};
        int   su[8];
        float ws[8];
        float4 xv[8];
#pragma unroll
        for (int u = 0; u < 8; u++) {
            int idx = i + 4 * u + j;
            bool act = idx < c;
            su[u] = act ? (int)raw[u] : n;   // in-bounds safe row when inactive
            ws[u] = act ? 1.f : 0.f;
        }
#pragma unroll
        for (int u = 0; u < 8; u++)
            xv[u] = *(const float4*)(xh + su[u] * INC + 8 * g);
#pragma unroll
        for (int u = 0; u < 8; u++) {
            const __half2* h2 = (const __half2*)&xv[u];
#pragma unroll
            for (int q = 0; q < 4; q++) {
                float2 f = __half22float2(h2[q]);
                acc[2 * q]     = fmaf(ws[u], f.x, acc[2 * q]);
                acc[2 * q + 1] = fmaf(ws[u], f.y, acc[2 * q + 1]);
            }
        }
    }
#pragma unroll
    for (int k = 0; k < 8; k++) {
        acc[k] += __shfl_down(acc[k], 32);
        acc[k] += __shfl_down(acc[k], 16);
    }
    if (j == 0) {
        __half2 o[4];
#pragma unroll
        for (int q = 0; q < 4; q++)
            o[q] = __floats2half2_rn(dn * acc[2 * q], dn * acc[2 * q + 1]);
        *(float4*)(xa + n * INC + 8 * g) = *(float4*)o;
    }
}

// ---- K5: MFMA GEMM + weighted-relu reduction + fused final scalar ----
__global__ __launch_bounds__(256) void k_gemm(const __half* __restrict__ xa,
                                              const __half* __restrict__ w1t,
                                              const float* __restrict__ b1,
                                              const float* __restrict__ dinv,
                                              const float* __restrict__ csum,
                                              float* __restrict__ v,
                                              unsigned int* __restrict__ done,
                                              const float* __restrict__ W2,
                                              const float* __restrict__ b2,
                                              const float* __restrict__ fcw,
                                              const float* __restrict__ fcb,
                                              float* __restrict__ out) {
    __shared__ float vloc[HIDC];
    int t = threadIdx.x;
    int w = t >> 6;           // wave id: owns cols [64w, 64w+64)
    int lane = t & 63;
    int m = lane & 15;
    int quad = lane >> 4;
    for (int i = t; i < HIDC; i += 256) vloc[i] = 0.f;
    __syncthreads();

    float bcol[4];
#pragma unroll
    for (int tt = 0; tt < 4; tt++) bcol[tt] = b1[w * 64 + tt * 16 + m];

    const half8* xa8 = (const half8*)xa;     // 8-half (16B) granules
    const half8* w8  = (const half8*)w1t;

    for (int gidx = blockIdx.x; gidx < NG; gidx += gridDim.x) {
        int base = gidx * 16;
        f32x4 acc[4] = {{0,0,0,0},{0,0,0,0},{0,0,0,0},{0,0,0,0}};
#pragma unroll
        for (int k0 = 0; k0 < 4; k0++) {
            half8 af = xa8[(base + m) * 16 + k0 * 4 + quad];
#pragma unroll
            for (int tt = 0; tt < 4; tt++) {
                int col = w * 64 + tt * 16 + m;
                half8 bf = w8[col * 16 + k0 * 4 + quad];
                acc[tt] = __builtin_amdgcn_mfma_f32_16x16x32_f16(af, bf, acc[tt], 0, 0, 0);
            }
        }
        float cr[4];
#pragma unroll
        for (int r = 0; r < 4; r++) {
            int n = base + quad * 4 + r;
            float dnn = dinv[n];
            cr[r] = dnn * (dnn + csum[n]);
        }
#pragma unroll
        for (int tt = 0; tt < 4; tt++) {
            float p = 0.f;
#pragma unroll
            for (int r = 0; r < 4; r++)
                p += cr[r] * fmaxf(acc[tt][r] + bcol[tt], 0.f);
            p += __shfl_down(p, 16);
            p += __shfl_down(p, 32);
            if (lane < 16) vloc[w * 64 + tt * 16 + lane] += p;  // wave-disjoint cols
        }
    }
    __syncthreads();
    atomicAdd(&v[t], vloc[t]);      // device-scope, distributed across blocks
    __threadfence();
    __shared__ bool last;
    if (t == 0) {
        unsigned int old = __hip_atomic_fetch_add(done, 1u, __ATOMIC_ACQ_REL,
                                                  __HIP_MEMORY_SCOPE_AGENT);
        last = (old == gridDim.x - 1);
    }
    __syncthreads();
    if (!last) return;
    // out = (1/N)*sum_t v[t]*u[t] + b2.fc_w + fc_b,  u = W2.fc_w
    float vt = __hip_atomic_load(&v[t], __ATOMIC_ACQUIRE, __HIP_MEMORY_SCOPE_AGENT);
    __shared__ float red[256];
    float u = 0.f;
#pragma unroll 4
    for (int jj = 0; jj < OUTC; jj++) u = fmaf(W2[t * OUTC + jj], fcw[jj], u);
    float contrib = vt * u * (1.0f / (float)NN);
    if (t < OUTC) contrib += b2[t] * fcw[t];
    red[t] = contrib;
    __syncthreads();
    for (int s = 128; s > 0; s >>= 1) {
        if (t < s) red[t] += red[t + s];
        __syncthreads();
    }
    if (t == 0) out[0] = red[0] + fcb[0];
}

extern "C" void kernel_launch(void* const* d_in, const int* in_sizes, int n_in,
                              void* d_out, int out_size, void* d_ws, size_t ws_size,
                              hipStream_t stream) {
    const float* x   = (const float*)d_in[0];
    const int*   ei  = (const int*)d_in[1];
    const float* W1  = (const float*)d_in[2];
    const float* b1  = (const float*)d_in[3];
    const float* W2  = (const float*)d_in[4];
    const float* b2  = (const float*)d_in[5];
    const float* fcw = (const float*)d_in[6];
    const float* fcb = (const float*)d_in[7];
    float* out = (float*)d_out;

    char* ws = (char*)d_ws;
    unsigned int*   done   = (unsigned int*)(ws + OFF_DONE);
    float*          v      = (float*)(ws + OFF_V);
    int*            cnt    = (int*)(ws + OFF_CNT);
    float*          dinv   = (float*)(ws + OFF_DINV);
    float*          csum   = (float*)(ws + OFF_CSUM);
    unsigned short* ell    = (unsigned short*)(ws + OFF_ELL);
    __half*         xh     = (__half*)(ws + OFF_XH);
    __half*         xa     = (__half*)(ws + OFF_XA);
    unsigned short* cpart  = (unsigned short*)(ws + OFF_CPART);
    float*          cspart = (float*)(ws + OFF_CSP);
    __half*         w1t    = (__half*)(ws + OFF_W1T);

    k_count<<<FB, 1024, 0, stream>>>(ei, cpart, v, done);
    k_scan<<<10, 1024, 0, stream>>>(cpart, cnt, dinv);
    k_prep<<<FB + CB + HB + TB, 1024, 0, stream>>>(ei, x, W1, dinv, cpart, ell,
                                                   cspart, xh, w1t);
    k_agg<<<AB + 40, 256, 0, stream>>>(x, xh, dinv, cnt, ell, cspart, csum, xa);
    k_gemm<<<GG, 256, 0, stream>>>(xa, w1t, b1, dinv, csum, v, done,
                                   W2, b2, fcw, fcb, out);
}